// Round 1
// baseline (472.898 us; speedup 1.0000x reference)
//
#include <hip/hip_runtime.h>
#include <math.h>

#define B 8
#define N 1024
#define L 16
#define D 256
#define H 4
#define DH 64
#define NLAYERS 2

// -------- workspace layout (floats) --------
// h      : B*N*D          = 2097152
// Wh     : B*H*N*DH       = 2097152
// hp     : B*H*N*DH       = 2097152
// srcv   : B*H*N          = 32768
// dstv   : B*H*N          = 32768
// rowmax : B*H*N          = 32768
// rowsum : B*H*N          = 32768
// total ~ 25.7 MB

// node_feat[b,n,d] = mean_l emb[nodes[b,n,l], d]
__global__ __launch_bounds__(256) void k_nodefeat(const int* __restrict__ nodes,
                                                  const float* __restrict__ emb,
                                                  float* __restrict__ h) {
    int bn = blockIdx.x;
    int d = threadIdx.x;
    const int* np = nodes + bn * L;
    float s = 0.f;
#pragma unroll
    for (int l = 0; l < L; ++l) {
        s += emb[np[l] * D + d];
    }
    h[bn * D + d] = s * (1.0f / L);
}

// Wh[b,h,n,k] = sum_d h[b,n,d] * W[layer,h,d,k]
// GEMM: (8192 x 256) @ (256 x 64) per head. Tile 64x64, thread = 4x4.
__global__ __launch_bounds__(256) void k_wh(const float* __restrict__ h,
                                            const float* __restrict__ W,
                                            float* __restrict__ Wh, int layer) {
    __shared__ float As[16][65];  // As[k][r]
    __shared__ float Bs[16][65];  // Bs[k][c]
    int tid = threadIdx.x;
    int tx = tid & 15;   // col group (k within head)
    int ty = tid >> 4;   // row group
    int r0 = blockIdx.x * 64;
    int hh = blockIdx.y;
    const float* Wl = W + ((layer * H + hh) * D) * DH;  // [d][k]
    float acc[4][4] = {};
    int cb = tid & 63, kb = tid >> 6;
    for (int kk = 0; kk < D; kk += 16) {
        // load A tile: h rows r0..r0+63, cols kk..kk+15 -> As[k][r]
#pragma unroll
        for (int rr = ty; rr < 64; rr += 16) {
            As[tx][rr] = h[(r0 + rr) * D + kk + tx];
        }
        // load B tile: Wl[kk+k][c] -> Bs[k][c]
#pragma unroll
        for (int k2 = kb; k2 < 16; k2 += 4) {
            Bs[k2][cb] = Wl[(kk + k2) * DH + cb];
        }
        __syncthreads();
#pragma unroll
        for (int k2 = 0; k2 < 16; ++k2) {
            float a[4], bb[4];
#pragma unroll
            for (int i = 0; i < 4; ++i) a[i] = As[k2][ty * 4 + i];
#pragma unroll
            for (int j = 0; j < 4; ++j) bb[j] = Bs[k2][tx * 4 + j];
#pragma unroll
            for (int i = 0; i < 4; ++i)
#pragma unroll
                for (int j = 0; j < 4; ++j) acc[i][j] += a[i] * bb[j];
        }
        __syncthreads();
    }
    // write: Wh[((b*H+hh)*N + n)*DH + c]
#pragma unroll
    for (int i = 0; i < 4; ++i) {
        int r = r0 + ty * 4 + i;
        int b = r >> 10, n = r & 1023;
        float4 v = make_float4(acc[i][0], acc[i][1], acc[i][2], acc[i][3]);
        *(float4*)&Wh[((b * H + hh) * N + n) * DH + tx * 4] = v;
    }
}

// src[bh,n] = sum_k Wh[bh,n,k]*a_src[l,h,k]; same for dst. One wave per row.
__global__ __launch_bounds__(256) void k_srcdst(const float* __restrict__ Wh,
                                                const float* __restrict__ a_src,
                                                const float* __restrict__ a_dst,
                                                float* __restrict__ srcv,
                                                float* __restrict__ dstv, int layer) {
    int g = blockIdx.x * 4 + (threadIdx.x >> 6);  // row in [0, B*H*N)
    int lane = threadIdx.x & 63;
    int bh = g >> 10;
    int hh = bh & (H - 1);
    float w = Wh[g * DH + lane];
    float s = w * a_src[(layer * H + hh) * DH + lane];
    float dd = w * a_dst[(layer * H + hh) * DH + lane];
#pragma unroll
    for (int off = 32; off; off >>= 1) {
        s += __shfl_xor(s, off, 64);
        dd += __shfl_xor(dd, off, 64);
    }
    if (lane == 0) { srcv[g] = s; dstv[g] = dd; }
}

// Per-row softmax stats over masked e[n,m] = lrelu(src[n]+dst[m]).
// Block per (b,n); wave w = head w; lane scans m with stride 64.
__global__ __launch_bounds__(256) void k_rowstats(const int* __restrict__ adj,
                                                  const float* __restrict__ srcv,
                                                  const float* __restrict__ dstv,
                                                  float* __restrict__ rowmax,
                                                  float* __restrict__ rowsum) {
    int bn = blockIdx.x;
    int b = bn >> 10, n = bn & 1023;
    int hh = threadIdx.x >> 6, lane = threadIdx.x & 63;
    int bh = b * H + hh;
    const int* arow = adj + (long)bn * N;
    const float* dstp = dstv + bh * N;
    float src = srcv[bh * N + n];
    float mx = -1e30f, sum = 0.f;
#pragma unroll
    for (int it = 0; it < N / 64; ++it) {
        int m = lane + it * 64;
        int a = arow[m];
        bool mask = (a != 0) || (m == n);
        float e = src + dstp[m];
        e = e > 0.f ? e : 0.2f * e;
        float nm = mask ? fmaxf(mx, e) : mx;
        sum = sum * __expf(mx - nm) + (mask ? __expf(e - nm) : 0.f);
        mx = nm;
    }
    // wave reduce (mx, sum)
#pragma unroll
    for (int off = 32; off; off >>= 1) {
        float mo = __shfl_xor(mx, off, 64);
        float so = __shfl_xor(sum, off, 64);
        float M = fmaxf(mx, mo);
        sum = sum * __expf(mx - M) + so * __expf(mo - M);
        mx = M;
    }
    if (lane == 0) {
        rowmax[bh * N + n] = mx;
        rowsum[bh * N + n] = sum;
    }
}

// h_prime[bh, n0..n0+63, :] = sum_m alpha[n,m] * Wh[bh,m,:]
// alpha regenerated per 64x64 tile into LDS; thread computes 4 rows x 4 cols.
__global__ __launch_bounds__(256) void k_attn(const int* __restrict__ adj,
                                              const float* __restrict__ srcv,
                                              const float* __restrict__ dstv,
                                              const float* __restrict__ rowmax,
                                              const float* __restrict__ rowsum,
                                              const float* __restrict__ Wh,
                                              float* __restrict__ hp) {
    __shared__ float alpha_lds[64][65];  // [r][mi]
    __shared__ float wh_lds[64][68];     // [mi][k], 16B-aligned rows
    int tid = threadIdx.x;
    int bt = blockIdx.x;
    int bh = bt >> 4;  // b*H+h
    int nt = bt & 15;
    int n0 = nt * 64;
    int b = bh >> 2;
    const long adjbase = ((long)(b * N + n0)) * N;
    int tx = tid & 15, ty = tid >> 4;
    int wsub = tid >> 6;  // wave id 0..3
    int mi1 = tid & 63;
    float acc[4][4] = {};
    for (int mt = 0; mt < 16; ++mt) {
        int m0 = mt * 64;
        // stage Wh tile into LDS (wave w loads rows w, w+4, ...)
        for (int mi = wsub; mi < 64; mi += 4) {
            wh_lds[mi][mi1] = Wh[(bh * N + m0 + mi) * DH + mi1];
        }
        float dsts = dstv[bh * N + m0 + mi1];
        // stage alpha tile: thread handles row r = rr*4+wsub, col mi1
        for (int rr = 0; rr < 16; ++rr) {
            int r = rr * 4 + wsub;
            int n = n0 + r;
            float src = srcv[bh * N + n];
            float mx = rowmax[bh * N + n];
            float inv = 1.0f / rowsum[bh * N + n];
            int a = adj[adjbase + (long)r * N + m0 + mi1];
            float e = src + dsts;
            e = e > 0.f ? e : 0.2f * e;
            float p = 0.f;
            if (a != 0 || (n == m0 + mi1)) p = __expf(e - mx) * inv;
            alpha_lds[r][mi1] = p;
        }
        __syncthreads();
#pragma unroll 4
        for (int mi = 0; mi < 64; ++mi) {
            float4 wv = *(const float4*)&wh_lds[mi][tx * 4];
            float a0 = alpha_lds[ty * 4 + 0][mi];
            float a1 = alpha_lds[ty * 4 + 1][mi];
            float a2 = alpha_lds[ty * 4 + 2][mi];
            float a3 = alpha_lds[ty * 4 + 3][mi];
            acc[0][0] += a0 * wv.x; acc[0][1] += a0 * wv.y; acc[0][2] += a0 * wv.z; acc[0][3] += a0 * wv.w;
            acc[1][0] += a1 * wv.x; acc[1][1] += a1 * wv.y; acc[1][2] += a1 * wv.z; acc[1][3] += a1 * wv.w;
            acc[2][0] += a2 * wv.x; acc[2][1] += a2 * wv.y; acc[2][2] += a2 * wv.z; acc[2][3] += a2 * wv.w;
            acc[3][0] += a3 * wv.x; acc[3][1] += a3 * wv.y; acc[3][2] += a3 * wv.z; acc[3][3] += a3 * wv.w;
        }
        __syncthreads();
    }
#pragma unroll
    for (int i = 0; i < 4; ++i) {
        int n = n0 + ty * 4 + i;
        float4 v = make_float4(acc[i][0], acc[i][1], acc[i][2], acc[i][3]);
        *(float4*)&hp[(bh * N + n) * DH + tx * 4] = v;
    }
}

// out[bn,c] = LN(h[bn,c] + hp[b, c/64, n, c%64]) * scale + bias
__global__ __launch_bounds__(256) void k_ln(const float* __restrict__ h,
                                            const float* __restrict__ hp,
                                            const float* __restrict__ scale,
                                            const float* __restrict__ bias,
                                            float* __restrict__ out, int layer) {
    __shared__ float red[8];
    int bn = blockIdx.x;
    int b = bn >> 10, n = bn & 1023;
    int c = threadIdx.x;
    int hh = c >> 6, k = c & 63;
    float x = h[bn * D + c] + hp[((b * H + hh) * N + n) * DH + k];
    float s = x, s2 = x * x;
#pragma unroll
    for (int off = 32; off; off >>= 1) {
        s += __shfl_xor(s, off, 64);
        s2 += __shfl_xor(s2, off, 64);
    }
    int w = c >> 6, lane = c & 63;
    if (lane == 0) { red[w] = s; red[4 + w] = s2; }
    __syncthreads();
    s = red[0] + red[1] + red[2] + red[3];
    s2 = red[4] + red[5] + red[6] + red[7];
    float mu = s * (1.0f / D);
    float var = s2 * (1.0f / D) - mu * mu;
    float r = rsqrtf(var + 1e-5f);
    out[bn * D + c] = (x - mu) * r * scale[layer * D + c] + bias[layer * D + c];
}

__global__ void k_len(const int* __restrict__ len, float* __restrict__ out) {
    int i = threadIdx.x;
    if (i < B) out[i] = (float)len[i];
}

extern "C" void kernel_launch(void* const* d_in, const int* in_sizes, int n_in,
                              void* d_out, int out_size, void* d_ws, size_t ws_size,
                              hipStream_t stream) {
    const int* cfg_adj = (const int*)d_in[0];
    const int* cfg_nodes = (const int*)d_in[1];
    const int* cfg_len = (const int*)d_in[2];
    const float* emb = (const float*)d_in[3];
    const float* W = (const float*)d_in[4];
    const float* a_src = (const float*)d_in[5];
    const float* a_dst = (const float*)d_in[6];
    const float* ln_scale = (const float*)d_in[7];
    const float* ln_bias = (const float*)d_in[8];
    float* out = (float*)d_out;
    float* ws = (float*)d_ws;

    float* h = ws;
    float* Wh = h + (size_t)B * N * D;
    float* hp = Wh + (size_t)B * H * N * DH;
    float* srcv = hp + (size_t)B * H * N * DH;
    float* dstv = srcv + (size_t)B * H * N;
    float* rowmax = dstv + (size_t)B * H * N;
    float* rowsum = rowmax + (size_t)B * H * N;

    k_nodefeat<<<B * N, 256, 0, stream>>>(cfg_nodes, emb, h);
    for (int l = 0; l < NLAYERS; ++l) {
        dim3 g(128, 4);
        k_wh<<<g, 256, 0, stream>>>(h, W, Wh, l);
        k_srcdst<<<B * H * N / 4, 256, 0, stream>>>(Wh, a_src, a_dst, srcv, dstv, l);
        k_rowstats<<<B * N, 256, 0, stream>>>(cfg_adj, srcv, dstv, rowmax, rowsum);
        k_attn<<<B * H * 16, 256, 0, stream>>>(cfg_adj, srcv, dstv, rowmax, rowsum, Wh, hp);
        k_ln<<<B * N, 256, 0, stream>>>(h, hp, ln_scale, ln_bias,
                                        (l == NLAYERS - 1) ? out : h, l);
    }
    k_len<<<1, 64, 0, stream>>>(cfg_len, out + (size_t)B * N * D);
}

// Round 2
// 377.630 us; speedup vs baseline: 1.2523x; 1.2523x over previous
//
#include <hip/hip_runtime.h>
#include <math.h>

#define B 8
#define N 1024
#define L 16
#define D 256
#define H 4
#define DH 64
#define NLAYERS 2

typedef __attribute__((ext_vector_type(8))) short short8;
typedef __attribute__((ext_vector_type(4))) float f32x4;

__device__ inline unsigned short f2bf(float x) {
    unsigned u = __float_as_uint(x);
    u = (u + 0x7fff + ((u >> 16) & 1)) >> 16;  // RNE
    return (unsigned short)u;
}

// -------- workspace layout (floats) --------
// h      : B*N*D          = 2097152
// Wh     : B*H*N*DH       = 2097152   (fp32, for k_srcdst)
// hp     : B*H*N*DH       = 2097152
// srcv   : B*H*N          = 32768
// dstv   : B*H*N          = 32768
// rowmax : B*H*N          = 32768
// rowsum : B*H*N          = 32768
// WhT    : B*H*DH*N bf16  = 2097152 ushort (1048576 floats)
// total ~ 29.7 MB

// node_feat[b,n,d] = mean_l emb[nodes[b,n,l], d]
__global__ __launch_bounds__(256) void k_nodefeat(const int* __restrict__ nodes,
                                                  const float* __restrict__ emb,
                                                  float* __restrict__ h) {
    int bn = blockIdx.x;
    int d = threadIdx.x;
    const int* np = nodes + bn * L;
    float s = 0.f;
#pragma unroll
    for (int l = 0; l < L; ++l) {
        s += emb[np[l] * D + d];
    }
    h[bn * D + d] = s * (1.0f / L);
}

// Wh[b,h,n,k] = sum_d h[b,n,d] * W[layer,h,d,k]; also write WhT bf16 [bh][dh][n]
__global__ __launch_bounds__(256) void k_wh(const float* __restrict__ h,
                                            const float* __restrict__ W,
                                            float* __restrict__ Wh,
                                            unsigned short* __restrict__ WhT, int layer) {
    __shared__ float As[16][65];  // As[k][r]
    __shared__ float Bs[16][65];  // Bs[k][c]
    int tid = threadIdx.x;
    int tx = tid & 15;   // col group (dh)
    int ty = tid >> 4;   // row group
    int r0 = blockIdx.x * 64;
    int hh = blockIdx.y;
    const float* Wl = W + ((layer * H + hh) * D) * DH;  // [d][k]
    float acc[4][4] = {};
    int cb = tid & 63, kb = tid >> 6;
    for (int kk = 0; kk < D; kk += 16) {
#pragma unroll
        for (int rr = ty; rr < 64; rr += 16) {
            As[tx][rr] = h[(r0 + rr) * D + kk + tx];
        }
#pragma unroll
        for (int k2 = kb; k2 < 16; k2 += 4) {
            Bs[k2][cb] = Wl[(kk + k2) * DH + cb];
        }
        __syncthreads();
#pragma unroll
        for (int k2 = 0; k2 < 16; ++k2) {
            float a[4], bb[4];
#pragma unroll
            for (int i = 0; i < 4; ++i) a[i] = As[k2][ty * 4 + i];
#pragma unroll
            for (int j = 0; j < 4; ++j) bb[j] = Bs[k2][tx * 4 + j];
#pragma unroll
            for (int i = 0; i < 4; ++i)
#pragma unroll
                for (int j = 0; j < 4; ++j) acc[i][j] += a[i] * bb[j];
        }
        __syncthreads();
    }
    int b = r0 >> 10, n0b = r0 & 1023;
    int bh = b * H + hh;
#pragma unroll
    for (int i = 0; i < 4; ++i) {
        int n = n0b + ty * 4 + i;
        float4 v = make_float4(acc[i][0], acc[i][1], acc[i][2], acc[i][3]);
        *(float4*)&Wh[(bh * N + n) * DH + tx * 4] = v;
    }
    // transposed bf16 copy: WhT[(bh*DH + dh)*N + n]
#pragma unroll
    for (int j = 0; j < 4; ++j) {
        int dh = tx * 4 + j;
        ushort4 v;
        v.x = f2bf(acc[0][j]); v.y = f2bf(acc[1][j]);
        v.z = f2bf(acc[2][j]); v.w = f2bf(acc[3][j]);
        *(ushort4*)&WhT[((size_t)(bh * DH + dh)) * N + n0b + ty * 4] = v;
    }
}

// src[bh,n] = sum_k Wh[bh,n,k]*a_src[l,h,k]; same for dst. One wave per row.
__global__ __launch_bounds__(256) void k_srcdst(const float* __restrict__ Wh,
                                                const float* __restrict__ a_src,
                                                const float* __restrict__ a_dst,
                                                float* __restrict__ srcv,
                                                float* __restrict__ dstv, int layer) {
    int g = blockIdx.x * 4 + (threadIdx.x >> 6);  // row in [0, B*H*N)
    int lane = threadIdx.x & 63;
    int bh = g >> 10;
    int hh = bh & (H - 1);
    float w = Wh[g * DH + lane];
    float s = w * a_src[(layer * H + hh) * DH + lane];
    float dd = w * a_dst[(layer * H + hh) * DH + lane];
#pragma unroll
    for (int off = 32; off; off >>= 1) {
        s += __shfl_xor(s, off, 64);
        dd += __shfl_xor(dd, off, 64);
    }
    if (lane == 0) { srcv[g] = s; dstv[g] = dd; }
}

// Per-row softmax stats over masked e[n,m] = lrelu(src[n]+dst[m]).
__global__ __launch_bounds__(256) void k_rowstats(const int* __restrict__ adj,
                                                  const float* __restrict__ srcv,
                                                  const float* __restrict__ dstv,
                                                  float* __restrict__ rowmax,
                                                  float* __restrict__ rowsum) {
    int bn = blockIdx.x;
    int b = bn >> 10, n = bn & 1023;
    int hh = threadIdx.x >> 6, lane = threadIdx.x & 63;
    int bh = b * H + hh;
    const int* arow = adj + (long)bn * N;
    const float* dstp = dstv + bh * N;
    float src = srcv[bh * N + n];
    float mx = -1e30f, sum = 0.f;
#pragma unroll
    for (int it = 0; it < N / 64; ++it) {
        int m = lane + it * 64;
        int a = arow[m];
        bool mask = (a != 0) || (m == n);
        float e = src + dstp[m];
        e = e > 0.f ? e : 0.2f * e;
        float nm = mask ? fmaxf(mx, e) : mx;
        sum = sum * __expf(mx - nm) + (mask ? __expf(e - nm) : 0.f);
        mx = nm;
    }
#pragma unroll
    for (int off = 32; off; off >>= 1) {
        float mo = __shfl_xor(mx, off, 64);
        float so = __shfl_xor(sum, off, 64);
        float M = fmaxf(mx, mo);
        sum = sum * __expf(mx - M) + so * __expf(mo - M);
        mx = M;
    }
    if (lane == 0) {
        rowmax[bh * N + n] = mx;
        rowsum[bh * N + n] = sum;
    }
}

// h_prime = alpha @ Wh via bf16 MFMA 16x16x32.
// Block = (bh, n-tile of 64). Wave w computes rows n0+16w..+15 x all 64 dh.
// A fragment (alpha) generated in-register: A[m=lane&15][k=quad*8+j],
// k-dim = attention column m (8 consecutive -> vector adj/dstv loads).
// B fragment from WhT bf16 [bh][dh][m]: 8 consecutive bf16 = 16B load.
__global__ __launch_bounds__(256) void k_attn(const int* __restrict__ adj,
                                              const float* __restrict__ srcv,
                                              const float* __restrict__ dstv,
                                              const float* __restrict__ rowmax,
                                              const float* __restrict__ rowsum,
                                              const unsigned short* __restrict__ WhT,
                                              float* __restrict__ hp) {
    int tid = threadIdx.x;
    int bt = blockIdx.x;
    int bh = bt >> 4;   // b*H+h
    int nt = bt & 15;
    int n0 = nt * 64;
    int b = bh >> 2;
    int w = tid >> 6;          // wave 0..3
    int lane = tid & 63;
    int rowLane = lane & 15;   // A-row within 16 / C-col within 16
    int quad = lane >> 4;
    int n = n0 + w * 16 + rowLane;  // alpha row this lane generates
    const int* arow = adj + ((long)(b * N + n)) * N;
    const float* dstp = dstv + bh * N;
    float src = srcv[bh * N + n];
    float mx = rowmax[bh * N + n];
    float inv = 1.0f / rowsum[bh * N + n];

    f32x4 acc[4] = {};
    for (int mt = 0; mt < 16; ++mt) {
#pragma unroll
        for (int kk = 0; kk < 2; ++kk) {
            int mbase = mt * 64 + kk * 32 + quad * 8;
            int4 a0 = *(const int4*)(arow + mbase);
            int4 a1 = *(const int4*)(arow + mbase + 4);
            float4 d0 = *(const float4*)(dstp + mbase);
            float4 d1 = *(const float4*)(dstp + mbase + 4);
            int aa[8] = {a0.x, a0.y, a0.z, a0.w, a1.x, a1.y, a1.z, a1.w};
            float dd[8] = {d0.x, d0.y, d0.z, d0.w, d1.x, d1.y, d1.z, d1.w};
            short8 af;
#pragma unroll
            for (int j = 0; j < 8; ++j) {
                float e = src + dd[j];
                e = e > 0.f ? e : 0.2f * e;
                float p = (aa[j] != 0 || (mbase + j == n)) ? __expf(e - mx) * inv : 0.f;
                af[j] = (short)f2bf(p);
            }
#pragma unroll
            for (int c = 0; c < 4; ++c) {
                short8 bf = *(const short8*)&WhT[((size_t)(bh * DH + c * 16 + rowLane)) * N + mt * 64 + kk * 32 + quad * 8];
                acc[c] = __builtin_amdgcn_mfma_f32_16x16x32_bf16(af, bf, acc[c], 0, 0, 0);
            }
        }
    }
    // C/D: col=lane&15, row=quad*4+reg
#pragma unroll
    for (int c = 0; c < 4; ++c) {
#pragma unroll
        for (int r = 0; r < 4; ++r) {
            int nout = n0 + w * 16 + quad * 4 + r;
            hp[(bh * N + nout) * DH + c * 16 + rowLane] = acc[c][r];
        }
    }
}

// out[bn,c] = LN(h[bn,c] + hp[b, c/64, n, c%64]) * scale + bias
__global__ __launch_bounds__(256) void k_ln(const float* __restrict__ h,
                                            const float* __restrict__ hp,
                                            const float* __restrict__ scale,
                                            const float* __restrict__ bias,
                                            float* __restrict__ out, int layer) {
    __shared__ float red[8];
    int bn = blockIdx.x;
    int b = bn >> 10, n = bn & 1023;
    int c = threadIdx.x;
    int hh = c >> 6, k = c & 63;
    float x = h[bn * D + c] + hp[((b * H + hh) * N + n) * DH + k];
    float s = x, s2 = x * x;
#pragma unroll
    for (int off = 32; off; off >>= 1) {
        s += __shfl_xor(s, off, 64);
        s2 += __shfl_xor(s2, off, 64);
    }
    int w = c >> 6, lane = c & 63;
    if (lane == 0) { red[w] = s; red[4 + w] = s2; }
    __syncthreads();
    s = red[0] + red[1] + red[2] + red[3];
    s2 = red[4] + red[5] + red[6] + red[7];
    float mu = s * (1.0f / D);
    float var = s2 * (1.0f / D) - mu * mu;
    float r = rsqrtf(var + 1e-5f);
    out[bn * D + c] = (x - mu) * r * scale[layer * D + c] + bias[layer * D + c];
}

__global__ void k_len(const int* __restrict__ len, float* __restrict__ out) {
    int i = threadIdx.x;
    if (i < B) out[i] = (float)len[i];
}

extern "C" void kernel_launch(void* const* d_in, const int* in_sizes, int n_in,
                              void* d_out, int out_size, void* d_ws, size_t ws_size,
                              hipStream_t stream) {
    const int* cfg_adj = (const int*)d_in[0];
    const int* cfg_nodes = (const int*)d_in[1];
    const int* cfg_len = (const int*)d_in[2];
    const float* emb = (const float*)d_in[3];
    const float* W = (const float*)d_in[4];
    const float* a_src = (const float*)d_in[5];
    const float* a_dst = (const float*)d_in[6];
    const float* ln_scale = (const float*)d_in[7];
    const float* ln_bias = (const float*)d_in[8];
    float* out = (float*)d_out;
    float* ws = (float*)d_ws;

    float* h = ws;
    float* Wh = h + (size_t)B * N * D;
    float* hp = Wh + (size_t)B * H * N * DH;
    float* srcv = hp + (size_t)B * H * N * DH;
    float* dstv = srcv + (size_t)B * H * N;
    float* rowmax = dstv + (size_t)B * H * N;
    float* rowsum = rowmax + (size_t)B * H * N;
    unsigned short* WhT = (unsigned short*)(rowsum + (size_t)B * H * N);

    k_nodefeat<<<B * N, 256, 0, stream>>>(cfg_nodes, emb, h);
    for (int l = 0; l < NLAYERS; ++l) {
        dim3 g(128, 4);
        k_wh<<<g, 256, 0, stream>>>(h, W, Wh, WhT, l);
        k_srcdst<<<B * H * N / 4, 256, 0, stream>>>(Wh, a_src, a_dst, srcv, dstv, l);
        k_rowstats<<<B * N, 256, 0, stream>>>(cfg_adj, srcv, dstv, rowmax, rowsum);
        k_attn<<<B * H * 16, 256, 0, stream>>>(cfg_adj, srcv, dstv, rowmax, rowsum, WhT, hp);
        k_ln<<<B * N, 256, 0, stream>>>(h, hp, ln_scale, ln_bias,
                                        (l == NLAYERS - 1) ? out : h, l);
    }
    k_len<<<1, 64, 0, stream>>>(cfg_len, out + (size_t)B * N * D);
}